// Round 1
// baseline (6271.910 us; speedup 1.0000x reference)
//
#include <hip/hip_runtime.h>

// Problem constants
#define B_    32
#define T_    2048
#define F_    64
#define H_    256
#define OUT_  64
#define G3_   768           // 3*H
#define NWG1  16            // layer-1 pipeline WGs
#define NWG2  16            // layer-2 pipeline WGs
#define TOTAL_WG (NWG1 + NWG2)
#define WGT   512           // threads per WG (8 waves)

// Tagged handoff rings. Each (slot, wg) block = 32 rows (batch) x 16 cols of
// 32-bit words {tag16<<16 | f16}; 2 KB per block. Tag = step+1 (1..2048), so
// zero-init means "empty" and ring reuse (depth 16 / 4) never aliases a live
// tag. Consumers poll the data words directly: same-word atomicity makes the
// value valid the moment its tag matches -> ONE global round trip per step
// (no flag store, no vmcnt(0) drain, no flag->data dependent load).
#define D1    16            // h1 ring depth (slots)
#define D2    4             // h2 ring depth
#define BLK_W 512           // u32 words per (slot, wg) block

#define XN_BYTES (B_ * T_ * F_ * 2)              // 8 MB fp16 LN(x), [T][B][F]
#define P1_OFF   XN_BYTES
#define P2_OFF   (P1_OFF + D1 * 16 * BLK_W * 4)  // +512 KB
#define PROG_OFF (P2_OFF + D2 * 16 * BLK_W * 4)  // +128 KB; prog: 16 lines x 64B

typedef _Float16 half8 __attribute__((ext_vector_type(8)));
typedef _Float16 half4 __attribute__((ext_vector_type(4)));
typedef float    f32x4 __attribute__((ext_vector_type(4)));
typedef unsigned long long u64;

#define TAGMASK 0xFFFF0000FFFF0000ull

#define LD_A(p)    __hip_atomic_load((p),  __ATOMIC_RELAXED, __HIP_MEMORY_SCOPE_AGENT)
#define ST_A(p, v) __hip_atomic_store((p), (v), __ATOMIC_RELAXED, __HIP_MEMORY_SCOPE_AGENT)

__device__ __forceinline__ float sigf(float x) {
    x = fminf(fmaxf(x, -30.f), 30.f);
    return 1.f / (1.f + __expf(-x));
}
__device__ __forceinline__ float tanhfast(float x) {
    x = fminf(fmaxf(x, -15.f), 15.f);
    float e = __expf(2.f * x);
    return (e - 1.f) / (e + 1.f);
}
__device__ __forceinline__ unsigned short f16b(float f) {
    union { _Float16 h; unsigned short u; } c; c.h = (_Float16)f; return c.u;
}

// ---------------------------------------------------------------------------
// Init: zero rings (tag 0 == empty) + prog, out = bias broadcast
// ---------------------------------------------------------------------------
__global__ void init_kernel(float* __restrict__ out, const float* __restrict__ bd,
                            unsigned int* __restrict__ packs, unsigned int* __restrict__ prog) {
    int t = blockIdx.x * 256 + threadIdx.x;              // 4096 threads
    if (t < B_ * OUT_) out[t] = bd[t & (OUT_ - 1)];
    if (t < 1024) prog[t] = 0u;
    for (int p = t; p < (D1 + D2) * 16 * BLK_W; p += 4096) packs[p] = 0u;  // p1|p2 contiguous
}

// ---------------------------------------------------------------------------
// LayerNorm over F=64, fp16 output TRANSPOSED to [T][B][F]. (unchanged)
// ---------------------------------------------------------------------------
__global__ __launch_bounds__(256) void ln_kernel(const float* __restrict__ x,
                                                 const float* __restrict__ gamma,
                                                 const float* __restrict__ beta,
                                                 _Float16* __restrict__ xn) {
    const int tid = threadIdx.x;
    const int r = tid >> 4, q = tid & 15;
    const size_t row = (size_t)blockIdx.x * 16 + r;      // = b*T + t
    const int b = (int)(row >> 11);
    const int t = (int)(row & 2047);
    const float4 v  = *(const float4*)(x + row * F_ + q * 4);
    const float4 g  = *(const float4*)(gamma + q * 4);
    const float4 be = *(const float4*)(beta + q * 4);
    float s = v.x + v.y + v.z + v.w;
    s += __shfl_xor(s, 1, 16); s += __shfl_xor(s, 2, 16);
    s += __shfl_xor(s, 4, 16); s += __shfl_xor(s, 8, 16);
    const float mu = s * (1.f / 64.f);
    const float dx = v.x - mu, dy = v.y - mu, dz = v.z - mu, dw = v.w - mu;
    float qq = dx * dx + dy * dy + dz * dz + dw * dw;
    qq += __shfl_xor(qq, 1, 16); qq += __shfl_xor(qq, 2, 16);
    qq += __shfl_xor(qq, 4, 16); qq += __shfl_xor(qq, 8, 16);
    const float rs = rsqrtf(qq * (1.f / 64.f) + 1e-3f);
    half4 o;
    o[0] = (_Float16)(dx * rs * g.x + be.x);
    o[1] = (_Float16)(dy * rs * g.y + be.y);
    o[2] = (_Float16)(dz * rs * g.z + be.z);
    o[3] = (_Float16)(dw * rs * g.w + be.w);
    *(half4*)(xn + ((size_t)t * B_ + b) * F_ + q * 4) = o;
}

// ---------------------------------------------------------------------------
// Dual-pipeline persistent GRU, tagged-word single-round-trip handoff.
//
// Safety audit (ring reuse / deadlock):
//  - L1 peers are mutually within 1 step (each step i needs all peers' i-1),
//    so slot i-16 is long consumed by peers when step i overwrites it.
//  - L2 lag bounded by back-pressure: L1 staging at step i requires
//    prog[w2] >= i-12, i.e. every L2 WG staged h1[i-13]; overwrite target is
//    h1[i-16] -> 3-slot margin. prog posted after the staging barrier.
//  - L2 peers mutually within 1 step -> h2 depth 4 safe (consumed at t-3).
//  - Stale tag (step s-16) = s-15 != s; producer can never run 16 ahead of a
//    still-waiting consumer (contradiction via prog / peer dependencies).
// ---------------------------------------------------------------------------
__global__ __launch_bounds__(WGT) void gru_main(
    const _Float16* __restrict__ xn,
    const float* __restrict__ k1, const float* __restrict__ rk1,
    const float* __restrict__ b1, const float* __restrict__ k2,
    const float* __restrict__ rk2, const float* __restrict__ b2,
    const float* __restrict__ wd, float* __restrict__ out,
    unsigned int* __restrict__ p1u, unsigned int* __restrict__ p2u,
    unsigned int* __restrict__ prog) {
    const int tid  = threadIdx.x;
    const int lane = tid & 63;
    const int wave = tid >> 6;           // 8 waves
    const int mt   = wave & 1;
    const int nt   = wave >> 1;          // 0..3
    const int ln   = lane & 15;
    const int quad = lane >> 4;

    __shared__ _Float16 h1s[32][264];    // 528B rows
    __shared__ _Float16 h2s[32][264];
    __shared__ float Cs[2][32][52];
    __shared__ float hs[32][16];

    const int  lc    = nt * 16 + ln;
    const bool valid = (lc < 48);
    const int  gate  = lc >> 4;
    const int  hidx  = lc & 15;
    const int  jl    = tid & 15;
    const int  bb    = tid >> 4;         // 0..31
    const int  m     = mt * 16 + ln;     // batch row for A fragments

    // zero LDS h state (step 0 consumes zeros; staging is skipped there)
    for (int p = tid; p < 32 * 264; p += WGT) {
        ((_Float16*)h1s)[p] = (_Float16)0.f;
        ((_Float16*)h2s)[p] = (_Float16)0.f;
    }
    __syncthreads();

    if (blockIdx.x < NWG1) {
        // ================= L1 pipeline =================
        const int w    = blockIdx.x;
        const int gcol = valid ? (gate * H_ + w * 16 + hidx) : 0;
        half8 fk1[2], frk1[8];
#pragma unroll
        for (int ks = 0; ks < 2; ++ks) {
            half8 f;
#pragma unroll
            for (int j = 0; j < 8; ++j) {
                const float v = k1[(ks * 32 + quad * 8 + j) * G3_ + gcol];
                f[j] = valid ? (_Float16)v : (_Float16)0.f;
            }
            fk1[ks] = f;
        }
#pragma unroll
        for (int ks = 0; ks < 8; ++ks) {
            half8 f;
#pragma unroll
            for (int j = 0; j < 8; ++j) {
                const float v = rk1[(ks * 32 + quad * 8 + j) * G3_ + gcol];
                f[j] = valid ? (_Float16)v : (_Float16)0.f;
            }
            frk1[ks] = f;
        }
        const int gc = w * 16 + jl;
        const float bxz = b1[gc],       bxr = b1[H_ + gc],       bxh = b1[2 * H_ + gc];
        const float bhz = b1[G3_ + gc], bhr = b1[G3_ + H_ + gc], bhh = b1[G3_ + 2 * H_ + gc];
        float h1m = 0.f;

        // staging map: 32 threads per source WG; thread loads 8 u64 (4 col-
        // quads x 4 row-octets) of the source's 2 KB tagged block.
        const int w2  = tid >> 5;                  // source WG 0..15
        const int t32 = tid & 31;
        const unsigned* bpp = prog + w2 * 16;      // L2 progress (back-pressure)

        for (int i = 0; i < T_; ++i) {
            // xn row loads issued BEFORE the poll -> L3 latency hides under it
            const _Float16* xr = xn + ((size_t)i * B_ + m) * F_ + quad * 8;
            const half8 ax0 = *(const half8*)(xr);
            const half8 ax1 = *(const half8*)(xr + 32);

            if (i > 0) {
                const unsigned tag = (unsigned)i;          // (i-1)+1
                const u64 tp = ((u64)tag << 48) | ((u64)tag << 16);
                const u64* src = (const u64*)(p1u + (((unsigned)(i - 1) & (D1 - 1)) * 16 + w2) * BLK_W);
                const unsigned bp = (i >= 13) ? (unsigned)(i - 12) : 0u;
                u64 q[8];
                for (;;) {
                    bool ok = (LD_A(bpp) >= bp);
#pragma unroll
                    for (int k = 0; k < 4; ++k) {
                        q[2 * k]     = LD_A(src + 64 * k + 2 * t32);
                        q[2 * k + 1] = LD_A(src + 64 * k + 2 * t32 + 1);
                    }
#pragma unroll
                    for (int k = 0; k < 8; ++k) ok &= ((q[k] & TAGMASK) == tp);
                    if (ok) break;
                    __builtin_amdgcn_s_sleep(1);
                }
                const int c0f = w2 * 16 + (t32 & 3) * 4;
                const int br  = t32 >> 2;
#pragma unroll
                for (int k = 0; k < 4; ++k) {
                    const u64 q0 = q[2 * k], q1 = q[2 * k + 1];
                    const u64 h4 = (q0 & 0xFFFFull) | ((q0 >> 16) & 0xFFFF0000ull)
                                 | ((q1 & 0xFFFFull) << 32) | ((q1 & 0xFFFF00000000ull) << 16);
                    *(u64*)(&h1s[br + 8 * k][c0f]) = h4;
                }
            }
            __syncthreads();                         // barrier A: staging done

            f32x4 c0 = {0.f, 0.f, 0.f, 0.f};
            c0 = __builtin_amdgcn_mfma_f32_16x16x32_f16(ax0, fk1[0], c0, 0, 0, 0);
            c0 = __builtin_amdgcn_mfma_f32_16x16x32_f16(ax1, fk1[1], c0, 0, 0, 0);
            f32x4 c1 = {0.f, 0.f, 0.f, 0.f};
#pragma unroll
            for (int ks = 0; ks < 8; ++ks) {
                half8 a1 = *(const half8*)(&h1s[m][ks * 32 + quad * 8]);
                c1 = __builtin_amdgcn_mfma_f32_16x16x32_f16(a1, frk1[ks], c1, 0, 0, 0);
            }
            if (valid) {
                const int r0 = mt * 16 + quad * 4;
#pragma unroll
                for (int rr = 0; rr < 4; ++rr) {
                    Cs[0][r0 + rr][lc] = c0[rr];
                    Cs[1][r0 + rr][lc] = c1[rr];
                }
            }
            __syncthreads();                         // barrier B: Cs ready

            // gates + tagged publish (fire-and-forget: no drain, no flag)
            {
                const float xz = Cs[0][bb][jl]      + bxz;
                const float xr2 = Cs[0][bb][16 + jl] + bxr;
                const float xh = Cs[0][bb][32 + jl] + bxh;
                const float rz = Cs[1][bb][jl]      + bhz;
                const float rr = Cs[1][bb][16 + jl] + bhr;
                const float rh = Cs[1][bb][32 + jl] + bhh;
                const float z  = sigf(xz + rz);
                const float r  = sigf(xr2 + rr);
                const float hh = tanhfast(xh + r * rh);
                h1m = z * h1m + (1.f - z) * hh;
                const unsigned wv = (unsigned)f16b(h1m) | ((unsigned)(i + 1) << 16);
                const unsigned pv = (unsigned)__shfl_xor((int)wv, 1);
                if ((jl & 1) == 0) {
                    const u64 v1 = (u64)wv | ((u64)pv << 32);
                    ST_A((u64*)(p1u + (((unsigned)i & (D1 - 1)) * 16 + w) * BLK_W + bb * 16 + jl), v1);
                }
            }
        }
    } else {
        // ================= L2 pipeline =================
        const int w    = blockIdx.x - NWG1;
        const int gcol = valid ? (gate * H_ + w * 16 + hidx) : 0;
        half8 fk2[8], frk2[8];
#pragma unroll
        for (int ks = 0; ks < 8; ++ks) {
            half8 f2, f3;
#pragma unroll
            for (int j = 0; j < 8; ++j) {
                const int k = ks * 32 + quad * 8 + j;
                const float v2 = k2 [k * G3_ + gcol];
                const float v3 = rk2[k * G3_ + gcol];
                f2[j] = valid ? (_Float16)v2 : (_Float16)0.f;
                f3[j] = valid ? (_Float16)v3 : (_Float16)0.f;
            }
            fk2[ks] = f2; frk2[ks] = f3;
        }
        const int gc = w * 16 + jl;
        const float bxz = b2[gc],       bxr = b2[H_ + gc],       bxh = b2[2 * H_ + gc];
        const float bhz = b2[G3_ + gc], bhr = b2[G3_ + H_ + gc], bhh = b2[G3_ + 2 * H_ + gc];
        float h2m = 0.f;

        // staging map: pk 0 = h1[t] (256 thr), pk 1 = h2[t-1] (256 thr);
        // 16 threads per source, 16 u64 each (128 B of the 2 KB block).
        const int pk  = tid >> 8;
        const int tt  = tid & 255;
        const int w2  = tt >> 4;
        const int l16 = tt & 15;

        for (int t = 0; t < T_; ++t) {
            if (pk == 0 || t > 0) {
                const unsigned tag = pk ? (unsigned)t : (unsigned)(t + 1);
                const u64 tp = ((u64)tag << 48) | ((u64)tag << 16);
                const u64* src = pk
                    ? (const u64*)(p2u + (((unsigned)(t - 1) & (D2 - 1)) * 16 + w2) * BLK_W)
                    : (const u64*)(p1u + (((unsigned)t & (D1 - 1)) * 16 + w2) * BLK_W);
                u64 q[16];
                for (;;) {
                    bool ok = true;
#pragma unroll
                    for (int k = 0; k < 8; ++k) {
                        q[2 * k]     = LD_A(src + 32 * k + 2 * l16);
                        q[2 * k + 1] = LD_A(src + 32 * k + 2 * l16 + 1);
                    }
#pragma unroll
                    for (int k = 0; k < 16; ++k) ok &= ((q[k] & TAGMASK) == tp);
                    if (ok) break;
                    __builtin_amdgcn_s_sleep(1);
                }
                _Float16 (*dst)[264] = pk ? h2s : h1s;
                const int c0f = w2 * 16 + (l16 & 3) * 4;
                const int br  = l16 >> 2;
#pragma unroll
                for (int k = 0; k < 8; ++k) {
                    const u64 q0 = q[2 * k], q1 = q[2 * k + 1];
                    const u64 h4 = (q0 & 0xFFFFull) | ((q0 >> 16) & 0xFFFF0000ull)
                                 | ((q1 & 0xFFFFull) << 32) | ((q1 & 0xFFFF00000000ull) << 16);
                    *(u64*)(&dst[br + 4 * k][c0f]) = h4;
                }
            }
            __syncthreads();                         // barrier A: staging done
            if (tid == 0) ST_A(&prog[w * 16], (unsigned)(t + 1));  // staged h1[t]

            f32x4 c2 = {0.f, 0.f, 0.f, 0.f};
            f32x4 c3 = c2;
#pragma unroll
            for (int ks = 0; ks < 8; ++ks) {
                half8 a1 = *(const half8*)(&h1s[m][ks * 32 + quad * 8]);
                half8 a2 = *(const half8*)(&h2s[m][ks * 32 + quad * 8]);
                c2 = __builtin_amdgcn_mfma_f32_16x16x32_f16(a1, fk2[ks],  c2, 0, 0, 0);
                c3 = __builtin_amdgcn_mfma_f32_16x16x32_f16(a2, frk2[ks], c3, 0, 0, 0);
            }
            if (valid) {
                const int r0 = mt * 16 + quad * 4;
#pragma unroll
                for (int rr = 0; rr < 4; ++rr) {
                    Cs[0][r0 + rr][lc] = c2[rr];
                    Cs[1][r0 + rr][lc] = c3[rr];
                }
            }
            __syncthreads();                         // barrier B: Cs ready

            // gates + tagged publish h2[t]
            {
                const float xz = Cs[0][bb][jl]      + bxz;
                const float xr2 = Cs[0][bb][16 + jl] + bxr;
                const float xh = Cs[0][bb][32 + jl] + bxh;
                const float rz = Cs[1][bb][jl]      + bhz;
                const float rr = Cs[1][bb][16 + jl] + bhr;
                const float rh = Cs[1][bb][32 + jl] + bhh;
                const float z  = sigf(xz + rz);
                const float r  = sigf(xr2 + rr);
                const float hh = tanhfast(xh + r * rh);
                h2m = z * h2m + (1.f - z) * hh;
                const unsigned wv = (unsigned)f16b(h2m) | ((unsigned)(t + 1) << 16);
                const unsigned pv = (unsigned)__shfl_xor((int)wv, 1);
                if ((jl & 1) == 0) {
                    const u64 v2 = (u64)wv | ((u64)pv << 32);
                    ST_A((u64*)(p2u + (((unsigned)t & (D2 - 1)) * 16 + w) * BLK_W + bb * 16 + jl), v2);
                }
            }
        }

        // ---- final dense: out[b][o] += sum_j h2[b][16w+j] * wd[16w+j][o]
        hs[bb][jl] = h2m;                // h2m = h2[T-1]
        __syncthreads();
        const int o  = tid & 63;
        const int bq = tid >> 6;         // 0..7
        for (int pass = 0; pass < 4; ++pass) {
            const int b = pass * 8 + bq;
            float acc = 0.f;
#pragma unroll
            for (int j = 0; j < 16; ++j) acc += hs[b][j] * wd[(w * 16 + j) * OUT_ + o];
            atomicAdd(&out[b * OUT_ + o], acc);
        }
    }
}

// ---------------------------------------------------------------------------
extern "C" void kernel_launch(void* const* d_in, const int* in_sizes, int n_in,
                              void* d_out, int out_size, void* d_ws, size_t ws_size,
                              hipStream_t stream) {
    const float* x     = (const float*)d_in[0];
    const float* gamma = (const float*)d_in[1];
    const float* beta  = (const float*)d_in[2];
    const float* k1    = (const float*)d_in[3];
    const float* rk1   = (const float*)d_in[4];
    const float* b1    = (const float*)d_in[5];
    const float* k2    = (const float*)d_in[6];
    const float* rk2   = (const float*)d_in[7];
    const float* b2    = (const float*)d_in[8];
    const float* wd    = (const float*)d_in[9];
    const float* bd    = (const float*)d_in[10];
    float* out = (float*)d_out;

    char* ws = (char*)d_ws;
    _Float16*     xn   = (_Float16*)ws;
    unsigned int* p1u  = (unsigned int*)(ws + P1_OFF);
    unsigned int* p2u  = (unsigned int*)(ws + P2_OFF);
    unsigned int* prog = (unsigned int*)(ws + PROG_OFF);

    hipLaunchKernelGGL(init_kernel, dim3(16), dim3(256), 0, stream, out, bd, p1u, prog);
    hipLaunchKernelGGL(ln_kernel, dim3(B_ * T_ / 16), dim3(256), 0, stream, x, gamma, beta, xn);

    void* args[] = {(void*)&xn, (void*)&k1, (void*)&rk1, (void*)&b1, (void*)&k2,
                    (void*)&rk2, (void*)&b2, (void*)&wd, (void*)&out,
                    (void*)&p1u, (void*)&p2u, (void*)&prog};
    hipLaunchCooperativeKernel((void*)gru_main, dim3(TOTAL_WG), dim3(WGT), args, 0, stream);
}